// Round 7
// baseline (153.008 us; speedup 1.0000x reference)
//
#include <hip/hip_runtime.h>
#include <math.h>

#define IN_F   128
#define HEADS  8
#define CPN    256   // channels per node = HEADS*OUT_F

typedef short s8v __attribute__((ext_vector_type(8)));
typedef float f4v __attribute__((ext_vector_type(4)));
typedef float f2v __attribute__((ext_vector_type(2)));

#if defined(__has_builtin)
#if __has_builtin(__builtin_amdgcn_cvt_pk_f32_fp8) && __has_builtin(__builtin_amdgcn_cvt_pk_fp8_f32)
#define HAVE_FP8 1
#endif
#endif
#ifndef HAVE_FP8
#define HAVE_FP8 0
#endif

__device__ __forceinline__ ushort f2b(float f) {   // f32 -> bf16 RNE
    unsigned u = __float_as_uint(f);
    return (ushort)((u + 0x7fffu + ((u >> 16) & 1)) >> 16);
}
__device__ __forceinline__ float blo(unsigned u) { return __uint_as_float(u << 16); }
__device__ __forceinline__ float bhi(unsigned u) { return __uint_as_float(u & 0xffff0000u); }

__device__ __forceinline__ bool is_i64(const int* __restrict__ ei) {
    return ei[1] == 0 && ei[3] == 0 && ei[5] == 0 && ei[7] == 0;
}

// ---------------------------------------------------------------------------
// Echo edge_index to output chunk 1 (as float) + normalized idx32, 4/thread.
__global__ void k_echo_cvt(const int* __restrict__ ei, int* __restrict__ idx32,
                           float* __restrict__ out_edge, int E2) {
    const int i0 = (blockIdx.x * blockDim.x + threadIdx.x) * 4;
    if (i0 >= E2) return;
    const bool f = is_i64(ei);
    int4 v;
    if (i0 + 3 < E2) {
        if (f) {
            const int4 a = *(const int4*)(ei + 2 * (size_t)i0);
            const int4 b = *(const int4*)(ei + 2 * (size_t)i0 + 4);
            v.x = a.x; v.y = a.z; v.z = b.x; v.w = b.z;
        } else {
            v = *(const int4*)(ei + i0);
        }
        *(int4*)(idx32 + i0) = v;
        float4 o = {(float)v.x, (float)v.y, (float)v.z, (float)v.w};
        *(float4*)(out_edge + i0) = o;
    } else {
        for (int i = i0; i < E2; ++i) {
            const int u = f ? ei[2 * (size_t)i] : ei[i];
            idx32[i] = u;
            out_edge[i] = (float)u;
        }
    }
}

// ---------------------------------------------------------------------------
// Histogram of targets + per-edge rank (returned old count), 4 edges/thread.
// 4 independent returning atomics in flight per thread.
__global__ void k_hist_rank(const int* __restrict__ ei, int* __restrict__ hist,
                            ushort* __restrict__ rank, int E) {
    const int e0 = (blockIdx.x * blockDim.x + threadIdx.x) * 4;
    if (e0 >= E) return;
    const bool f = is_i64(ei);
    if (e0 + 3 < E) {
        int v0, v1, v2, v3;
        if (f) {
            const int4 a = *(const int4*)(ei + 2 * (size_t)E + 2 * (size_t)e0);
            const int4 b = *(const int4*)(ei + 2 * (size_t)E + 2 * (size_t)e0 + 4);
            v0 = a.x; v1 = a.z; v2 = b.x; v3 = b.z;
        } else {
            const int4 a = *(const int4*)(ei + (size_t)E + e0);
            v0 = a.x; v1 = a.y; v2 = a.z; v3 = a.w;
        }
        ushort4 r;
        r.x = (ushort)atomicAdd(&hist[v0], 1);
        r.y = (ushort)atomicAdd(&hist[v1], 1);
        r.z = (ushort)atomicAdd(&hist[v2], 1);
        r.w = (ushort)atomicAdd(&hist[v3], 1);
        *(ushort4*)(rank + e0) = r;
    } else {
        for (int e = e0; e < E; ++e) {
            const int t = f ? ei[2 * (size_t)E + 2 * (size_t)e] : ei[(size_t)E + e];
            rank[e] = (ushort)atomicAdd(&hist[t], 1);
        }
    }
}

// ---------------------------------------------------------------------------
// Wt[528][128] bf16: rows 0-255 = W_proj cols, 256-511 = W_skip cols,
// 512-527 = score rows: w_s[h] = W_proj[:,32h:32h+32] @ scs[h]  (h<8 -> src,
// h>=8 -> tgt). s_src = x @ w_s exactly (linear algebra identity).
__global__ void k_prep_w(const float* __restrict__ Wp, const float* __restrict__ Wk,
                         const float* __restrict__ scs, const float* __restrict__ sct,
                         ushort* __restrict__ wt) {
    int i = blockIdx.x * blockDim.x + threadIdx.x;   // i = r*128 + k
    if (i >= 528 * 128) return;
    const int r = i >> 7, k = i & 127;
    float v;
    if (r < 512) {
        const float* W = (r < 256) ? Wp : Wk;
        v = W[k * CPN + (r & 255)];
    } else {
        const int idx = r - 512;                 // 0..15
        const int head = idx & 7;
        const float* sv = (idx < 8) ? scs : sct; // [1,8,32] flat
        const float* wrow = Wp + k * CPN + head * 32;
        const float* svh = sv + head * 32;
        float acc = 0.f;
#pragma unroll
        for (int f = 0; f < 32; ++f) acc += wrow[f] * svh[f];
        v = acc;
    }
    wt[i] = f2b(v);
}

// ---------------------------------------------------------------------------
// MFMA GEMM: [proj(fp8)||skip(bf16)||scores(f32)] = x @ Wt^T, in-register
// f32->bf16 conversion of x. Swapped operands: D col = node (lane&15), D rows
// = 4 consecutive channels -> 4B fp8 / 8B bf16 packed stores. 4 waves/block.
__global__ __launch_bounds__(256) void k_gemm(
        const float* __restrict__ x, const ushort* __restrict__ wt,
        unsigned char* __restrict__ projf8, ushort* __restrict__ skipb,
        float* __restrict__ s_src, float* __restrict__ s_tgt, int N) {
    const int w   = threadIdx.x >> 6;
    const int l   = threadIdx.x & 63;
    const int l15 = l & 15, l4 = l >> 4;
    const int node_base = blockIdx.x * 256 + w * 64;

    s8v xf[4][4];
#pragma unroll
    for (int sub = 0; sub < 4; ++sub) {
        int node = node_base + sub * 16 + l15;
        if (node >= N) node = N - 1;
        const float* row = x + (size_t)node * IN_F;
#pragma unroll
        for (int k4 = 0; k4 < 4; ++k4) {
            const float4 a = *(const float4*)(row + k4 * 32 + l4 * 8);
            const float4 b = *(const float4*)(row + k4 * 32 + l4 * 8 + 4);
            s8v f;
            f[0] = (short)f2b(a.x); f[1] = (short)f2b(a.y);
            f[2] = (short)f2b(a.z); f[3] = (short)f2b(a.w);
            f[4] = (short)f2b(b.x); f[5] = (short)f2b(b.y);
            f[6] = (short)f2b(b.z); f[7] = (short)f2b(b.w);
            xf[sub][k4] = f;
        }
    }

    for (int tc = 0; tc < 33; ++tc) {            // 32 channel tiles + scores
        s8v wf[4];
        const ushort* wrow = wt + (size_t)(tc * 16 + l15) * IN_F;
#pragma unroll
        for (int k4 = 0; k4 < 4; ++k4)
            wf[k4] = *(const s8v*)(wrow + k4 * 32 + l4 * 8);
#pragma unroll
        for (int sub = 0; sub < 4; ++sub) {
            f4v acc = {0.f, 0.f, 0.f, 0.f};
#pragma unroll
            for (int k4 = 0; k4 < 4; ++k4)
                acc = __builtin_amdgcn_mfma_f32_16x16x32_bf16(wf[k4], xf[sub][k4], acc, 0, 0, 0);
            const int node = node_base + sub * 16 + l15;
            if (node >= N) continue;
            if (tc < 16) {                        // proj -> fp8 (4B store)
                const int chb = tc * 16 + l4 * 4;
#if HAVE_FP8
                int pk = __builtin_amdgcn_cvt_pk_fp8_f32(acc[0], acc[1], 0, false);
                pk = __builtin_amdgcn_cvt_pk_fp8_f32(acc[2], acc[3], pk, true);
                *(int*)(projf8 + ((size_t)node << 8) + chb) = pk;
#else
                ushort4 o;
                o.x = f2b(acc[0]); o.y = f2b(acc[1]);
                o.z = f2b(acc[2]); o.w = f2b(acc[3]);
                *(ushort4*)((ushort*)projf8 + ((size_t)node << 8) + chb) = o;
#endif
            } else if (tc < 32) {                 // skip -> bf16 (8B store)
                const int chb = (tc & 15) * 16 + l4 * 4;
                ushort4 o;
                o.x = f2b(acc[0]); o.y = f2b(acc[1]);
                o.z = f2b(acc[2]); o.w = f2b(acc[3]);
                *(ushort4*)(skipb + (size_t)node * CPN + chb) = o;
            } else {                              // scores -> f32
#pragma unroll
                for (int j2 = 0; j2 < 4; ++j2) {
                    const int idx = l4 * 4 + j2;     // 0..15
                    if (idx < 8) s_src[node * HEADS + idx] = acc[j2];
                    else         s_tgt[node * HEADS + idx - 8] = acc[j2];
                }
            }
        }
    }
}

// ---------------------------------------------------------------------------
// Scan (CSR build): row_start = exclusive prefix of hist (immutable)
__global__ __launch_bounds__(256) void k_scan1(const int* __restrict__ hist,
                                               int* __restrict__ tmp_scan,
                                               int* __restrict__ partial, int N) {
    __shared__ int wsum[4];
    const int b = blockIdx.x, tid = threadIdx.x;
    const int lane = tid & 63, w = tid >> 6;
    const int base = b * 1024 + tid * 4;
    int v0 = (base + 0 < N) ? hist[base + 0] : 0;
    int v1 = (base + 1 < N) ? hist[base + 1] : 0;
    int v2 = (base + 2 < N) ? hist[base + 2] : 0;
    int v3 = (base + 3 < N) ? hist[base + 3] : 0;
    const int tsum = v0 + v1 + v2 + v3;
    int inc = tsum;
#pragma unroll
    for (int off = 1; off < 64; off <<= 1) {
        int y = __shfl_up(inc, off);
        if (lane >= off) inc += y;
    }
    if (lane == 63) wsum[w] = inc;
    __syncthreads();
    int woff = 0;
    for (int i = 0; i < w; ++i) woff += wsum[i];
    const int e0 = woff + inc - tsum;
    if (base + 0 < N) tmp_scan[base + 0] = e0;
    if (base + 1 < N) tmp_scan[base + 1] = e0 + v0;
    if (base + 2 < N) tmp_scan[base + 2] = e0 + v0 + v1;
    if (base + 3 < N) tmp_scan[base + 3] = e0 + v0 + v1 + v2;
    if (tid == 255) partial[b] = woff + inc;
}

// scan of block partials folded in via LDS (NB <= 128)
__global__ void k_scan3(const int* __restrict__ tmp_scan, const int* __restrict__ partial,
                        int* __restrict__ row_start, int N, int NB) {
    __shared__ int pref[128];
    if (threadIdx.x == 0) {
        int run = 0;
        for (int k = 0; k < NB; ++k) { pref[k] = run; run += partial[k]; }
    }
    __syncthreads();
    int i = blockIdx.x * blockDim.x + threadIdx.x;
    if (i < N) row_start[i] = tmp_scan[i] + pref[i >> 10];
}

// Atomic-free placement: pos = row_start[t] + rank[e]. 4 edges/thread.
__global__ void k_place(const int* __restrict__ idx32, const ushort* __restrict__ rank,
                        const int* __restrict__ row_start,
                        ushort* __restrict__ sorted_src, int E) {
    const int e0 = (blockIdx.x * blockDim.x + threadIdx.x) * 4;
    if (e0 >= E) return;
    if (e0 + 3 < E) {
        const int4    s = *(const int4*)(idx32 + e0);
        const int4    t = *(const int4*)(idx32 + (size_t)E + e0);
        const ushort4 r = *(const ushort4*)(rank + e0);
        sorted_src[row_start[t.x] + (int)r.x] = (ushort)s.x;
        sorted_src[row_start[t.y] + (int)r.y] = (ushort)s.y;
        sorted_src[row_start[t.z] + (int)r.z] = (ushort)s.z;
        sorted_src[row_start[t.w] + (int)r.w] = (ushort)s.w;
    } else {
        for (int e = e0; e < E; ++e)
            sorted_src[row_start[idx32[(size_t)E + e]] + (int)rank[e]] = (ushort)idx32[e];
    }
}

// ---------------------------------------------------------------------------
// One WAVE per target node; lane owns 4 consecutive channels (4B fp8 gathers).
// Register num/den accumulation, 4-edge unroll, fused skip+bias+ELU epilogue.
__global__ __launch_bounds__(256) void k_aggregate(
        const int* __restrict__ row_start, const ushort* __restrict__ sorted_src,
        const float* __restrict__ s_src, const float* __restrict__ s_tgt,
        const unsigned char* __restrict__ projf8, const ushort* __restrict__ skipb,
        const float* __restrict__ bias, float* __restrict__ out, int N, int E) {
    const int t = blockIdx.x * 4 + (threadIdx.x >> 6);
    if (t >= N) return;
    const int l   = threadIdx.x & 63;
    const int h   = l >> 3;          // head of this lane's 4 channels
    const int cb4 = l * 4;           // channel/byte base
    const int start = row_start[t];
    const int end   = (t + 1 < N) ? row_start[t + 1] : E;
    const float st = s_tgt[t * HEADS + h];

    float n0 = 0.f, n1 = 0.f, n2 = 0.f, n3 = 0.f, den = 0.f;

#if HAVE_FP8
#define LOADP(s)  *(const unsigned int*)(projf8 + ((size_t)(s) << 8) + cb4)
#define ACC(p, e) { f2v lo = __builtin_amdgcn_cvt_pk_f32_fp8((int)(p), false); \
                    f2v hi = __builtin_amdgcn_cvt_pk_f32_fp8((int)(p), true);  \
                    n0 += (e) * lo.x; n1 += (e) * lo.y;                        \
                    n2 += (e) * hi.x; n3 += (e) * hi.y; }
    unsigned int P0, P1, P2, P3;
#else
#define LOADP(s)  *(const uint2*)((const ushort*)projf8 + ((size_t)(s) << 8) + cb4)
#define ACC(p, e) { n0 += (e) * blo((p).x); n1 += (e) * bhi((p).x); \
                    n2 += (e) * blo((p).y); n3 += (e) * bhi((p).y); }
    uint2 P0, P1, P2, P3;
#endif

    int j = start;
    for (; j + 3 < end; j += 4) {
        const int s0 = sorted_src[j];
        const int s1 = sorted_src[j + 1];
        const int s2 = sorted_src[j + 2];
        const int s3 = sorted_src[j + 3];
        const float ss0 = s_src[s0 * HEADS + h];
        const float ss1 = s_src[s1 * HEADS + h];
        const float ss2 = s_src[s2 * HEADS + h];
        const float ss3 = s_src[s3 * HEADS + h];
        P0 = LOADP(s0); P1 = LOADP(s1); P2 = LOADP(s2); P3 = LOADP(s3);
        float c0 = ss0 + st; c0 = fmaxf(c0, 0.2f * c0);
        float c1 = ss1 + st; c1 = fmaxf(c1, 0.2f * c1);
        float c2 = ss2 + st; c2 = fmaxf(c2, 0.2f * c2);
        float c3 = ss3 + st; c3 = fmaxf(c3, 0.2f * c3);
        const float e0 = __expf(c0), e1 = __expf(c1);
        const float e2 = __expf(c2), e3 = __expf(c3);
        ACC(P0, e0); ACC(P1, e1); ACC(P2, e2); ACC(P3, e3);
        den += e0 + e1 + e2 + e3;
    }
    for (; j < end; ++j) {
        const int s0 = sorted_src[j];
        const float ss0 = s_src[s0 * HEADS + h];
        P0 = LOADP(s0);
        float c0 = ss0 + st; c0 = fmaxf(c0, 0.2f * c0);
        const float e0 = __expf(c0);
        ACC(P0, e0);
        den += e0;
    }

    const int idx = t * CPN + cb4;
    const uint2 skv = *(const uint2*)(skipb + idx);
    const float4 bv = *(const float4*)(bias + cb4);
    const float r = 1.f / (den + 1e-16f);
    float4 o;
    o.x = n0 * r + blo(skv.x) + bv.x;
    o.y = n1 * r + bhi(skv.x) + bv.y;
    o.z = n2 * r + blo(skv.y) + bv.z;
    o.w = n3 * r + bhi(skv.y) + bv.w;
    o.x = o.x > 0.f ? o.x : __expf(o.x) - 1.f;
    o.y = o.y > 0.f ? o.y : __expf(o.y) - 1.f;
    o.z = o.z > 0.f ? o.z : __expf(o.z) - 1.f;
    o.w = o.w > 0.f ? o.w : __expf(o.w) - 1.f;
    *(float4*)(out + idx) = o;
}

// ---------------------------------------------------------------------------
extern "C" void kernel_launch(void* const* d_in, const int* in_sizes, int n_in,
                              void* d_out, int out_size, void* d_ws, size_t ws_size,
                              hipStream_t stream) {
    const float* x    = (const float*)d_in[0];
    const int*   ei   = (const int*)d_in[1];
    const float* Wp   = (const float*)d_in[2];
    const float* Wk   = (const float*)d_in[3];
    const float* scs  = (const float*)d_in[4];
    const float* sct  = (const float*)d_in[5];
    const float* bias = (const float*)d_in[6];

    const int N = in_sizes[0] / IN_F;   // 50000
    const int E = in_sizes[1] / 2;      // 800000
    const int NB = (N + 1023) / 1024;   // 49

    float* out      = (float*)d_out;
    float* out_edge = out + (size_t)N * CPN;

    // workspace layout
    char* ws = (char*)d_ws;
    int*  idx32 = (int*)ws;
    size_t off = (size_t)2 * E * sizeof(int);
    off = (off + 255) & ~(size_t)255;
    int* hist       = (int*)(ws + off); off += (size_t)N * sizeof(int);
    int* tmp_scan   = (int*)(ws + off); off += (size_t)N * sizeof(int);
    int* partial    = (int*)(ws + off); off += 256 * sizeof(int);
    int* row_start  = (int*)(ws + off); off += (size_t)N * sizeof(int);
    ushort* rank       = (ushort*)(ws + off); off += (size_t)E * sizeof(ushort);
    ushort* sorted_src = (ushort*)(ws + off); off += (size_t)E * sizeof(ushort);
    off = (off + 255) & ~(size_t)255;
    ushort* wt = (ushort*)(ws + off); off += (size_t)528 * IN_F * sizeof(ushort);
    unsigned char* projf8 = (unsigned char*)(ws + off);
    off += (size_t)N * CPN * sizeof(ushort);   // reserve bf16 size (fallback-safe)
    ushort* skipb = (ushort*)(ws + off); off += (size_t)N * CPN * sizeof(ushort);
    off = (off + 255) & ~(size_t)255;
    float* s_src = (float*)(ws + off); off += (size_t)N * HEADS * sizeof(float);
    float* s_tgt = (float*)(ws + off); off += (size_t)N * HEADS * sizeof(float);

    hipMemsetAsync(hist, 0, (size_t)N * sizeof(int), stream);

    k_hist_rank<<<(E / 4 + 255) / 256, 256, 0, stream>>>(ei, hist, rank, E);
    k_echo_cvt<<<(2 * E / 4 + 255) / 256, 256, 0, stream>>>(ei, idx32, out_edge, 2 * E);

    k_prep_w<<<(528 * 128 + 255) / 256, 256, 0, stream>>>(Wp, Wk, scs, sct, wt);
    k_gemm<<<(N + 255) / 256, 256, 0, stream>>>(x, wt, projf8, skipb, s_src, s_tgt, N);

    k_scan1<<<NB, 256, 0, stream>>>(hist, tmp_scan, partial, N);
    k_scan3<<<(N + 255) / 256, 256, 0, stream>>>(tmp_scan, partial, row_start, N, NB);
    k_place<<<(E / 4 + 255) / 256, 256, 0, stream>>>(idx32, rank, row_start, sorted_src, E);

    k_aggregate<<<(N + 3) / 4, 256, 0, stream>>>(row_start, sorted_src, s_src, s_tgt,
                                                 projf8, skipb, bias, out, N, E);
}

// Round 8
// 132.804 us; speedup vs baseline: 1.1521x; 1.1521x over previous
//
#include <hip/hip_runtime.h>
#include <math.h>

#define IN_F   128
#define HEADS  8
#define CPN    256   // channels per node = HEADS*OUT_F
#define NBUCK  256   // coarse buckets: bucket = t >> 8
#define P1B    256   // blocks in k_count
#define P2B    128   // blocks in k_scatter

typedef short s8v __attribute__((ext_vector_type(8)));
typedef float f4v __attribute__((ext_vector_type(4)));
typedef float f2v __attribute__((ext_vector_type(2)));

#if defined(__has_builtin)
#if __has_builtin(__builtin_amdgcn_cvt_pk_f32_fp8) && __has_builtin(__builtin_amdgcn_cvt_pk_fp8_f32)
#define HAVE_FP8 1
#endif
#endif
#ifndef HAVE_FP8
#define HAVE_FP8 0
#endif

__device__ __forceinline__ ushort f2b(float f) {   // f32 -> bf16 RNE
    unsigned u = __float_as_uint(f);
    return (ushort)((u + 0x7fffu + ((u >> 16) & 1)) >> 16);
}
__device__ __forceinline__ float blo(unsigned u) { return __uint_as_float(u << 16); }
__device__ __forceinline__ float bhi(unsigned u) { return __uint_as_float(u & 0xffff0000u); }

__device__ __forceinline__ bool is_i64(const int* __restrict__ ei) {
    return ei[1] == 0 && ei[3] == 0 && ei[5] == 0 && ei[7] == 0;
}

// ---------------------------------------------------------------------------
// Echo edge_index to output chunk 1 (as float), 4/thread. Block 0 also zeroes
// the 512 ints of gcnt||gcursor (safe: consumers are later kernel launches).
__global__ void k_echo_cvt(const int* __restrict__ ei, float* __restrict__ out_edge,
                           int* __restrict__ gz, int E2) {
    const int tid = threadIdx.x;
    if (blockIdx.x == 0) { gz[tid] = 0; gz[tid + 256] = 0; }
    const int i0 = (blockIdx.x * blockDim.x + tid) * 4;
    if (i0 >= E2) return;
    const bool f = is_i64(ei);
    if (i0 + 3 < E2) {
        int4 v;
        if (f) {
            const int4 a = *(const int4*)(ei + 2 * (size_t)i0);
            const int4 b = *(const int4*)(ei + 2 * (size_t)i0 + 4);
            v.x = a.x; v.y = a.z; v.z = b.x; v.w = b.z;
        } else {
            v = *(const int4*)(ei + i0);
        }
        float4 o = {(float)v.x, (float)v.y, (float)v.z, (float)v.w};
        *(float4*)(out_edge + i0) = o;
    } else {
        for (int i = i0; i < E2; ++i)
            out_edge[i] = (float)(f ? ei[2 * (size_t)i] : ei[i]);
    }
}

// ---------------------------------------------------------------------------
// Pass 1: coarse-bucket counts. LDS histogram per block, one global
// atomicAdd per (block,bucket).
__global__ __launch_bounds__(256) void k_count(const int* __restrict__ ei,
                                               int* __restrict__ gcnt, int E) {
    __shared__ int lcnt[NBUCK];
    const int tid = threadIdx.x;
    lcnt[tid] = 0;
    __syncthreads();
    const bool f = is_i64(ei);
    const int chunk = (E + P1B - 1) / P1B;
    const int lo = blockIdx.x * chunk, hi = min(E, lo + chunk);
    for (int e = lo + tid; e < hi; e += 256) {
        const int t = f ? ei[2 * ((size_t)E + e)] : ei[(size_t)E + e];
        atomicAdd(&lcnt[t >> 8], 1);
    }
    __syncthreads();
    if (lcnt[tid]) atomicAdd(&gcnt[tid], lcnt[tid]);
}

// ---------------------------------------------------------------------------
// Pass 2: scatter (t&255,s) pairs into coarse buckets. Per-block space is
// reserved with one atomicAdd(gcursor[b], lcnt[b]) per bucket; per-edge
// positions come from LDS atomics.
__global__ __launch_bounds__(256) void k_scatter(const int* __restrict__ ei,
                                                 const int* __restrict__ gcnt,
                                                 int* __restrict__ gcursor,
                                                 unsigned* __restrict__ pairs, int E) {
    __shared__ int bbase[NBUCK], lcnt[NBUCK], lbase[NBUCK], wsum[4];
    const int tid = threadIdx.x;
    // exclusive scan of gcnt -> bbase
    const int v = gcnt[tid];
    int inc = v;
#pragma unroll
    for (int off = 1; off < 64; off <<= 1) {
        int y = __shfl_up(inc, off);
        if ((tid & 63) >= off) inc += y;
    }
    if ((tid & 63) == 63) wsum[tid >> 6] = inc;
    __syncthreads();
    int woff = 0;
    for (int i = 0; i < (tid >> 6); ++i) woff += wsum[i];
    bbase[tid] = woff + inc - v;
    lcnt[tid] = 0;
    __syncthreads();

    const bool f = is_i64(ei);
    const int chunk = (E + P2B - 1) / P2B;
    const int lo = blockIdx.x * chunk, hi = min(E, lo + chunk);
    for (int e = lo + tid; e < hi; e += 256) {
        const int t = f ? ei[2 * ((size_t)E + e)] : ei[(size_t)E + e];
        atomicAdd(&lcnt[t >> 8], 1);
    }
    __syncthreads();
    lbase[tid] = lcnt[tid] ? atomicAdd(&gcursor[tid], lcnt[tid]) : 0;
    __syncthreads();
    lcnt[tid] = 0;
    __syncthreads();
    for (int e = lo + tid; e < hi; e += 256) {
        int t, s;
        if (f) { t = ei[2 * ((size_t)E + e)]; s = ei[2 * (size_t)e]; }
        else   { t = ei[(size_t)E + e];       s = ei[e]; }
        const int bk = t >> 8;
        const int r = atomicAdd(&lcnt[bk], 1);
        pairs[bbase[bk] + lbase[bk] + r] = ((unsigned)(t & 255) << 16) | (unsigned)s;
    }
}

// ---------------------------------------------------------------------------
// Pass 3: one block per coarse bucket. Fine 256-bin LDS histogram + scan ->
// row_start + sorted_src. No global atomics.
__global__ __launch_bounds__(256) void k_bsort(const unsigned* __restrict__ pairs,
                                               const int* __restrict__ gcnt,
                                               ushort* __restrict__ sorted_src,
                                               int* __restrict__ row_start, int N) {
    __shared__ int fh[256], fs[256], wsumA[4], wsumB[4];
    __shared__ int sbase, scnt;
    const int tid = threadIdx.x, b = blockIdx.x;

    // exclusive scan of gcnt; thread b holds this bucket's base
    const int v = gcnt[tid];
    int inc = v;
#pragma unroll
    for (int off = 1; off < 64; off <<= 1) {
        int y = __shfl_up(inc, off);
        if ((tid & 63) >= off) inc += y;
    }
    if ((tid & 63) == 63) wsumA[tid >> 6] = inc;
    __syncthreads();
    int woff = 0;
    for (int i = 0; i < (tid >> 6); ++i) woff += wsumA[i];
    if (tid == b) { sbase = woff + inc - v; scnt = v; }
    fh[tid] = 0;
    __syncthreads();
    const int base = sbase, cnt = scnt;

    for (int i = tid; i < cnt; i += 256)
        atomicAdd(&fh[pairs[base + i] >> 16], 1);
    __syncthreads();

    // exclusive scan of fh -> fs
    const int hv = fh[tid];
    int hinc = hv;
#pragma unroll
    for (int off = 1; off < 64; off <<= 1) {
        int y = __shfl_up(hinc, off);
        if ((tid & 63) >= off) hinc += y;
    }
    if ((tid & 63) == 63) wsumB[tid >> 6] = hinc;
    __syncthreads();
    int hoff = 0;
    for (int i = 0; i < (tid >> 6); ++i) hoff += wsumB[i];
    fs[tid] = hoff + hinc - hv;

    const int t = (b << 8) + tid;
    if (t < N) row_start[t] = base + fs[tid];
    fh[tid] = 0;
    __syncthreads();

    for (int i = tid; i < cnt; i += 256) {
        const unsigned p = pairs[base + i];
        const int tl = p >> 16;
        const int r = atomicAdd(&fh[tl], 1);
        sorted_src[base + fs[tl] + r] = (ushort)(p & 0xFFFFu);
    }
}

// ---------------------------------------------------------------------------
// Wt[528][128] bf16: rows 0-255 = W_proj cols, 256-511 = W_skip cols,
// 512-527 = score rows: w_s[h] = W_proj[:,32h:32h+32] @ scs[h]  (h<8 -> src,
// h>=8 -> tgt). s_src = x @ w_s exactly (linear algebra identity).
__global__ void k_prep_w(const float* __restrict__ Wp, const float* __restrict__ Wk,
                         const float* __restrict__ scs, const float* __restrict__ sct,
                         ushort* __restrict__ wt) {
    int i = blockIdx.x * blockDim.x + threadIdx.x;   // i = r*128 + k
    if (i >= 528 * 128) return;
    const int r = i >> 7, k = i & 127;
    float v;
    if (r < 512) {
        const float* W = (r < 256) ? Wp : Wk;
        v = W[k * CPN + (r & 255)];
    } else {
        const int idx = r - 512;                 // 0..15
        const int head = idx & 7;
        const float* sv = (idx < 8) ? scs : sct; // [1,8,32] flat
        const float* wrow = Wp + k * CPN + head * 32;
        const float* svh = sv + head * 32;
        float acc = 0.f;
#pragma unroll
        for (int f = 0; f < 32; ++f) acc += wrow[f] * svh[f];
        v = acc;
    }
    wt[i] = f2b(v);
}

// ---------------------------------------------------------------------------
// MFMA GEMM: [proj(fp8)||skip(bf16)||scores(f32)] = x @ Wt^T, in-register
// f32->bf16 conversion of x. Swapped operands: D col = node (lane&15), D rows
// = 4 consecutive channels -> 4B fp8 / 8B bf16 packed stores. 4 waves/block.
__global__ __launch_bounds__(256) void k_gemm(
        const float* __restrict__ x, const ushort* __restrict__ wt,
        unsigned char* __restrict__ projf8, ushort* __restrict__ skipb,
        float* __restrict__ s_src, float* __restrict__ s_tgt, int N) {
    const int w   = threadIdx.x >> 6;
    const int l   = threadIdx.x & 63;
    const int l15 = l & 15, l4 = l >> 4;
    const int node_base = blockIdx.x * 256 + w * 64;

    s8v xf[4][4];
#pragma unroll
    for (int sub = 0; sub < 4; ++sub) {
        int node = node_base + sub * 16 + l15;
        if (node >= N) node = N - 1;
        const float* row = x + (size_t)node * IN_F;
#pragma unroll
        for (int k4 = 0; k4 < 4; ++k4) {
            const float4 a = *(const float4*)(row + k4 * 32 + l4 * 8);
            const float4 b = *(const float4*)(row + k4 * 32 + l4 * 8 + 4);
            s8v f;
            f[0] = (short)f2b(a.x); f[1] = (short)f2b(a.y);
            f[2] = (short)f2b(a.z); f[3] = (short)f2b(a.w);
            f[4] = (short)f2b(b.x); f[5] = (short)f2b(b.y);
            f[6] = (short)f2b(b.z); f[7] = (short)f2b(b.w);
            xf[sub][k4] = f;
        }
    }

    for (int tc = 0; tc < 33; ++tc) {            // 32 channel tiles + scores
        s8v wf[4];
        const ushort* wrow = wt + (size_t)(tc * 16 + l15) * IN_F;
#pragma unroll
        for (int k4 = 0; k4 < 4; ++k4)
            wf[k4] = *(const s8v*)(wrow + k4 * 32 + l4 * 8);
#pragma unroll
        for (int sub = 0; sub < 4; ++sub) {
            f4v acc = {0.f, 0.f, 0.f, 0.f};
#pragma unroll
            for (int k4 = 0; k4 < 4; ++k4)
                acc = __builtin_amdgcn_mfma_f32_16x16x32_bf16(wf[k4], xf[sub][k4], acc, 0, 0, 0);
            const int node = node_base + sub * 16 + l15;
            if (node >= N) continue;
            if (tc < 16) {                        // proj -> fp8 (4B store)
                const int chb = tc * 16 + l4 * 4;
#if HAVE_FP8
                int pk = __builtin_amdgcn_cvt_pk_fp8_f32(acc[0], acc[1], 0, false);
                pk = __builtin_amdgcn_cvt_pk_fp8_f32(acc[2], acc[3], pk, true);
                *(int*)(projf8 + ((size_t)node << 8) + chb) = pk;
#else
                ushort4 o;
                o.x = f2b(acc[0]); o.y = f2b(acc[1]);
                o.z = f2b(acc[2]); o.w = f2b(acc[3]);
                *(ushort4*)((ushort*)projf8 + ((size_t)node << 8) + chb) = o;
#endif
            } else if (tc < 32) {                 // skip -> bf16 (8B store)
                const int chb = (tc & 15) * 16 + l4 * 4;
                ushort4 o;
                o.x = f2b(acc[0]); o.y = f2b(acc[1]);
                o.z = f2b(acc[2]); o.w = f2b(acc[3]);
                *(ushort4*)(skipb + (size_t)node * CPN + chb) = o;
            } else {                              // scores -> f32
#pragma unroll
                for (int j2 = 0; j2 < 4; ++j2) {
                    const int idx = l4 * 4 + j2;     // 0..15
                    if (idx < 8) s_src[node * HEADS + idx] = acc[j2];
                    else         s_tgt[node * HEADS + idx - 8] = acc[j2];
                }
            }
        }
    }
}

// ---------------------------------------------------------------------------
// One WAVE per target node; lane owns 4 consecutive channels (4B fp8 gathers).
// Register num/den accumulation, 4-edge unroll, fused skip+bias+ELU epilogue.
__global__ __launch_bounds__(256) void k_aggregate(
        const int* __restrict__ row_start, const ushort* __restrict__ sorted_src,
        const float* __restrict__ s_src, const float* __restrict__ s_tgt,
        const unsigned char* __restrict__ projf8, const ushort* __restrict__ skipb,
        const float* __restrict__ bias, float* __restrict__ out, int N, int E) {
    const int t = blockIdx.x * 4 + (threadIdx.x >> 6);
    if (t >= N) return;
    const int l   = threadIdx.x & 63;
    const int h   = l >> 3;          // head of this lane's 4 channels
    const int cb4 = l * 4;           // channel/byte base
    const int start = row_start[t];
    const int end   = (t + 1 < N) ? row_start[t + 1] : E;
    const float st = s_tgt[t * HEADS + h];

    float n0 = 0.f, n1 = 0.f, n2 = 0.f, n3 = 0.f, den = 0.f;

#if HAVE_FP8
#define LOADP(s)  *(const unsigned int*)(projf8 + ((size_t)(s) << 8) + cb4)
#define ACC(p, e) { f2v lo = __builtin_amdgcn_cvt_pk_f32_fp8((int)(p), false); \
                    f2v hi = __builtin_amdgcn_cvt_pk_f32_fp8((int)(p), true);  \
                    n0 += (e) * lo.x; n1 += (e) * lo.y;                        \
                    n2 += (e) * hi.x; n3 += (e) * hi.y; }
    unsigned int P0, P1, P2, P3;
#else
#define LOADP(s)  *(const uint2*)((const ushort*)projf8 + ((size_t)(s) << 8) + cb4)
#define ACC(p, e) { n0 += (e) * blo((p).x); n1 += (e) * bhi((p).x); \
                    n2 += (e) * blo((p).y); n3 += (e) * bhi((p).y); }
    uint2 P0, P1, P2, P3;
#endif

    int j = start;
    for (; j + 3 < end; j += 4) {
        const int s0 = sorted_src[j];
        const int s1 = sorted_src[j + 1];
        const int s2 = sorted_src[j + 2];
        const int s3 = sorted_src[j + 3];
        const float ss0 = s_src[s0 * HEADS + h];
        const float ss1 = s_src[s1 * HEADS + h];
        const float ss2 = s_src[s2 * HEADS + h];
        const float ss3 = s_src[s3 * HEADS + h];
        P0 = LOADP(s0); P1 = LOADP(s1); P2 = LOADP(s2); P3 = LOADP(s3);
        float c0 = ss0 + st; c0 = fmaxf(c0, 0.2f * c0);
        float c1 = ss1 + st; c1 = fmaxf(c1, 0.2f * c1);
        float c2 = ss2 + st; c2 = fmaxf(c2, 0.2f * c2);
        float c3 = ss3 + st; c3 = fmaxf(c3, 0.2f * c3);
        const float e0 = __expf(c0), e1 = __expf(c1);
        const float e2 = __expf(c2), e3 = __expf(c3);
        ACC(P0, e0); ACC(P1, e1); ACC(P2, e2); ACC(P3, e3);
        den += e0 + e1 + e2 + e3;
    }
    for (; j < end; ++j) {
        const int s0 = sorted_src[j];
        const float ss0 = s_src[s0 * HEADS + h];
        P0 = LOADP(s0);
        float c0 = ss0 + st; c0 = fmaxf(c0, 0.2f * c0);
        const float e0 = __expf(c0);
        ACC(P0, e0);
        den += e0;
    }

    const int idx = t * CPN + cb4;
    const uint2 skv = *(const uint2*)(skipb + idx);
    const float4 bv = *(const float4*)(bias + cb4);
    const float r = 1.f / (den + 1e-16f);
    float4 o;
    o.x = n0 * r + blo(skv.x) + bv.x;
    o.y = n1 * r + bhi(skv.x) + bv.y;
    o.z = n2 * r + blo(skv.y) + bv.z;
    o.w = n3 * r + bhi(skv.y) + bv.w;
    o.x = o.x > 0.f ? o.x : __expf(o.x) - 1.f;
    o.y = o.y > 0.f ? o.y : __expf(o.y) - 1.f;
    o.z = o.z > 0.f ? o.z : __expf(o.z) - 1.f;
    o.w = o.w > 0.f ? o.w : __expf(o.w) - 1.f;
    *(float4*)(out + idx) = o;
}

// ---------------------------------------------------------------------------
extern "C" void kernel_launch(void* const* d_in, const int* in_sizes, int n_in,
                              void* d_out, int out_size, void* d_ws, size_t ws_size,
                              hipStream_t stream) {
    const float* x    = (const float*)d_in[0];
    const int*   ei   = (const int*)d_in[1];
    const float* Wp   = (const float*)d_in[2];
    const float* Wk   = (const float*)d_in[3];
    const float* scs  = (const float*)d_in[4];
    const float* sct  = (const float*)d_in[5];
    const float* bias = (const float*)d_in[6];

    const int N = in_sizes[0] / IN_F;   // 50000
    const int E = in_sizes[1] / 2;      // 800000
    const int NBUSE = (N + 255) >> 8;   // 196 used coarse buckets

    float* out      = (float*)d_out;
    float* out_edge = out + (size_t)N * CPN;

    // workspace layout
    char* ws = (char*)d_ws;
    size_t off = 0;
    int* gz = (int*)(ws + off); off += 512 * sizeof(int);   // gcnt||gcursor
    int* gcnt = gz;
    int* gcursor = gz + 256;
    unsigned* pairs = (unsigned*)(ws + off); off += (size_t)E * sizeof(unsigned);
    int* row_start  = (int*)(ws + off); off += (size_t)N * sizeof(int);
    ushort* sorted_src = (ushort*)(ws + off); off += (size_t)E * sizeof(ushort);
    off = (off + 255) & ~(size_t)255;
    ushort* wt = (ushort*)(ws + off); off += (size_t)528 * IN_F * sizeof(ushort);
    unsigned char* projf8 = (unsigned char*)(ws + off);
    off += (size_t)N * CPN * sizeof(ushort);   // reserve bf16 size (fallback-safe)
    ushort* skipb = (ushort*)(ws + off); off += (size_t)N * CPN * sizeof(ushort);
    off = (off + 255) & ~(size_t)255;
    float* s_src = (float*)(ws + off); off += (size_t)N * HEADS * sizeof(float);
    float* s_tgt = (float*)(ws + off); off += (size_t)N * HEADS * sizeof(float);

    k_echo_cvt<<<(2 * E / 4 + 255) / 256, 256, 0, stream>>>(ei, out_edge, gz, 2 * E);
    k_count<<<P1B, 256, 0, stream>>>(ei, gcnt, E);
    k_scatter<<<P2B, 256, 0, stream>>>(ei, gcnt, gcursor, pairs, E);
    k_bsort<<<NBUSE, 256, 0, stream>>>(pairs, gcnt, sorted_src, row_start, N);

    k_prep_w<<<(528 * 128 + 255) / 256, 256, 0, stream>>>(Wp, Wk, scs, sct, wt);
    k_gemm<<<(N + 255) / 256, 256, 0, stream>>>(x, wt, projf8, skipb, s_src, s_tgt, N);

    k_aggregate<<<(N + 3) / 4, 256, 0, stream>>>(row_start, sorted_src, s_src, s_tgt,
                                                 projf8, skipb, bias, out, N, E);
}